// Round 2
// baseline (1155.841 us; speedup 1.0000x reference)
//
#include <hip/hip_runtime.h>
#include <hip/hip_bf16.h>
#include <hip/hip_fp16.h>
#include <math.h>

// Causal conv via four-step FFT, N = 2T = 131072 = N1(512) x N2(256).
// z = bf16(x) + i*h ; one complex FFT serves both real signals.
// n = n1 + 512*n2 (n1 in [0,512), n2 in [0,256), nonzero n2 < 128).
// buf[seq][k2][n1] half2, k2 NATURAL order (256 rows x 512).
// ws: [0,1MiB) cpx tw[m] = exp(-2pi i m/N); [2MiB,+256MiB) buf.
//
// R1: packed-FP32 complex arithmetic (VOP3P v_pk_*_f32), table twiddles.
// R2: k_mid = one wave per Hermitian column pair (2x ILP, no __syncthreads);
//     all twiddle-power chains replaced by direct tw[] gathers (exact powers,
//     zero dep chains); K1 first-stage fft8 specialized for zero upper half.

#define TLEN 65536
#define NFFT 131072
#define NN1 512
#define NN2 256

#define WFENCE() asm volatile("s_waitcnt lgkmcnt(0)" ::: "memory")

typedef float cpx __attribute__((ext_vector_type(2)));

static __device__ __forceinline__ cpx mkc(float a, float b) { cpx r; r.x = a; r.y = b; return r; }
static __device__ __forceinline__ cpx h2c(__half2 h) { float2 f = __half22float2(h); return mkc(f.x, f.y); }
static __device__ __forceinline__ __half2 c2h(cpx c) { return __float22half2_rn(make_float2(c.x, c.y)); }

// ---- packed complex primitives (one VOP3P inst per complex add/sub) ----
static __device__ __forceinline__ cpx cadd(cpx a, cpx b) {
  cpx d; asm("v_pk_add_f32 %0, %1, %2" : "=v"(d) : "v"(a), "v"(b)); return d;
}
static __device__ __forceinline__ cpx csub(cpx a, cpx b) {
  cpx d; asm("v_pk_add_f32 %0, %1, %2 neg_lo:[0,1] neg_hi:[0,1]" : "=v"(d) : "v"(a), "v"(b)); return d;
}
static __device__ __forceinline__ cpx cscale(cpx a, cpx c) {
  cpx d; asm("v_pk_mul_f32 %0, %1, %2" : "=v"(d) : "v"(a), "v"(c)); return d;
}
// d = a*b : t = (a.x*b.x, a.x*b.y); d = (-a.y*b.y + t.lo, a.y*b.x + t.hi)
static __device__ __forceinline__ cpx cmul(cpx a, cpx b) {
  cpx t, d;
  asm("v_pk_mul_f32 %0, %1, %2 op_sel:[0,0] op_sel_hi:[0,1]" : "=v"(t) : "v"(a), "v"(b));
  asm("v_pk_fma_f32 %0, %1, %2, %3 op_sel:[1,1,0] op_sel_hi:[1,0,1] neg_lo:[1,0,0]"
      : "=v"(d) : "v"(a), "v"(b), "v"(t));
  return d;
}
// d = a*conj(b) : (a.x b.x + a.y b.y, a.y b.x - a.x b.y)
static __device__ __forceinline__ cpx cmulc(cpx a, cpx b) {
  cpx t, d;
  asm("v_pk_mul_f32 %0, %1, %2 op_sel:[0,0] op_sel_hi:[0,1]" : "=v"(t) : "v"(a), "v"(b));
  asm("v_pk_fma_f32 %0, %1, %2, %3 op_sel:[1,1,0] op_sel_hi:[1,0,1] neg_hi:[0,0,1]"
      : "=v"(d) : "v"(a), "v"(b), "v"(t));
  return d;
}
// d = s*i*a : S=+1 -> (-a.y, a.x) ; S=-1 -> (a.y, -a.x)
template <int S> static __device__ __forceinline__ cpx cmuli(cpx a) {
  cpx z = mkc(0.f, 0.f); cpx d;
  if constexpr (S == 1)
    asm("v_pk_add_f32 %0, %1, %2 op_sel:[1,0] op_sel_hi:[0,0] neg_lo:[1,0]" : "=v"(d) : "v"(a), "v"(z));
  else
    asm("v_pk_add_f32 %0, %1, %2 op_sel:[1,0] op_sel_hi:[0,0] neg_hi:[1,0]" : "=v"(d) : "v"(a), "v"(z));
  return d;
}
// C * (d.x - s d.y, s d.x + d.y)
template <int S> static __device__ __forceinline__ cpx cw1(cpx d, cpx Cc) {
  cpx u;
  if constexpr (S == -1)
    asm("v_pk_add_f32 %0, %1, %1 op_sel:[0,1] op_sel_hi:[1,0] neg_hi:[0,1]" : "=v"(u) : "v"(d));
  else
    asm("v_pk_add_f32 %0, %1, %1 op_sel:[0,1] op_sel_hi:[0,1] neg_lo:[0,1]" : "=v"(u) : "v"(d));
  return cscale(u, Cc);
}
// C * (-d.x - s d.y, s d.x - d.y)
template <int S> static __device__ __forceinline__ cpx cw3(cpx d, cpx Cc) {
  cpx u;
  if constexpr (S == -1)
    asm("v_pk_add_f32 %0, %1, %1 op_sel:[1,0] op_sel_hi:[0,1] neg_lo:[0,1] neg_hi:[1,1]" : "=v"(u) : "v"(d));
  else
    asm("v_pk_add_f32 %0, %1, %1 op_sel:[0,1] op_sel_hi:[0,1] neg_lo:[1,1] neg_hi:[0,1]" : "=v"(u) : "v"(d));
  return cscale(u, Cc);
}

// out[k] = sum_j in[j] * W8^{S*jk}, W8 = e^{-2pi i/8}. Natural order.
template <int S>
__device__ __forceinline__ void fft8(cpx v[8]) {
  cpx Cc; Cc.x = 0.70710678118654752f; Cc.y = 0.70710678118654752f;
  cpx b0 = cadd(v[0], v[4]), b4 = csub(v[0], v[4]);
  cpx b1 = cadd(v[1], v[5]), d1 = csub(v[1], v[5]);
  cpx b2 = cadd(v[2], v[6]), d2 = csub(v[2], v[6]);
  cpx b3 = cadd(v[3], v[7]), d3 = csub(v[3], v[7]);
  cpx b5 = cw1<S>(d1, Cc);
  cpx b6 = cmuli<S>(d2);
  cpx b7 = cw3<S>(d3, Cc);
  cpx c0 = cadd(b0, b2), c2 = csub(b0, b2);
  cpx c1 = cadd(b1, b3), e3 = csub(b1, b3);
  cpx c3 = cmuli<S>(e3);
  cpx c4 = cadd(b4, b6), c6 = csub(b4, b6);
  cpx c5 = cadd(b5, b7), e7 = csub(b5, b7);
  cpx c7 = cmuli<S>(e7);
  v[0] = cadd(c0, c1); v[4] = csub(c0, c1);
  v[2] = cadd(c2, c3); v[6] = csub(c2, c3);
  v[1] = cadd(c4, c5); v[5] = csub(c4, c5);
  v[3] = cadd(c6, c7); v[7] = csub(c6, c7);
}

// fft8 with v[4..7] == 0 implied (zero-padded upper half): first level free.
template <int S>
__device__ __forceinline__ void fft8h(cpx v[8]) {
  cpx Cc; Cc.x = 0.70710678118654752f; Cc.y = 0.70710678118654752f;
  cpx b5 = cw1<S>(v[1], Cc);
  cpx b6 = cmuli<S>(v[2]);
  cpx b7 = cw3<S>(v[3], Cc);
  cpx c0 = cadd(v[0], v[2]), c2 = csub(v[0], v[2]);
  cpx c1 = cadd(v[1], v[3]), e3 = csub(v[1], v[3]);
  cpx c3 = cmuli<S>(e3);
  cpx c4 = cadd(v[0], b6), c6 = csub(v[0], b6);
  cpx c5 = cadd(b5, b7), e7 = csub(b5, b7);
  cpx c7 = cmuli<S>(e7);
  v[0] = cadd(c0, c1); v[4] = csub(c0, c1);
  v[2] = cadd(c2, c3); v[6] = csub(c2, c3);
  v[1] = cadd(c4, c5); v[5] = csub(c4, c5);
  v[3] = cadd(c6, c7); v[7] = csub(c6, c7);
}

template <int S>
__device__ __forceinline__ void fft4(cpx v[4]) {
  cpx t0 = cadd(v[0], v[2]), t1 = csub(v[0], v[2]);
  cpx t2 = cadd(v[1], v[3]), t3 = csub(v[1], v[3]);
  cpx it3 = cmuli<S>(t3);
  v[0] = cadd(t0, t2); v[2] = csub(t0, t2);
  v[1] = cadd(t1, it3); v[3] = csub(t1, it3);
}

__global__ void k_init_tw(cpx* __restrict__ tw) {
  int m = blockIdx.x * 256 + threadIdx.x;
  double ang = (double)m * (-2.0 * 3.14159265358979323846 / (double)NFFT);
  tw[m] = mkc((float)cos(ang), (float)sin(ang));
}

// ---------------------------------------------------------------------------
// K1: forward FFT-256 over n2 for 16 n1 per block + twiddle W_N^{n1 k2}.
// Register FFT 256 = 8x8x4. Stage twiddle powers = direct tw[] gathers
// (pw1[j]=W256^{l5 j}, pw2[j]=W256^{8 bb j}); big twiddle = tw[n1*k2].
// ---------------------------------------------------------------------------
__global__ __launch_bounds__(256, 3) void k_fwd_inner(
    const float* __restrict__ x, const float* __restrict__ h,
    __half2* __restrict__ buf, const cpx* __restrict__ tw) {
  __shared__ __half2 tz[128 * 18];   // z tile [n2][n1], stride 18
  __shared__ cpx xch[4 * 512];       // per-wave exchange scratch
  __shared__ __half2 to[256 * 17];   // out tile [k2][n1l], stride 17
  const int tid = threadIdx.x;
  const int lane = tid & 63;
  const int wid = tid >> 6;
  const int s = blockIdx.x >> 5;
  const int n1b = (blockIdx.x & 31) * 16;
  // stage-in: 64B-granule rows (4 lanes x float4)
  const float* xp = x + (size_t)s * TLEN;
  const float* hp = h + (size_t)s * TLEN;
  {
    int a = tid & 3, q = tid >> 2;
#pragma unroll
    for (int iter = 0; iter < 2; ++iter) {
      int n2 = q + 64 * iter;
      size_t gi = (size_t)(n1b + 4 * a) + (size_t)512 * n2;
      float4 xv = *(const float4*)(xp + gi);
      float4 hv = *(const float4*)(hp + gi);
      float xs[4] = {xv.x, xv.y, xv.z, xv.w};
      float hs[4] = {hv.x, hv.y, hv.z, hv.w};
#pragma unroll
      for (int c = 0; c < 4; ++c) {
        float xb = __bfloat162float(__float2bfloat16(xs[c]));
        tz[18 * n2 + 4 * a + c] = __float22half2_rn(make_float2(xb, hs[c]));
      }
    }
  }
  cpx* X = xch + wid * 512;
  const int f = lane >> 5;
  const int l5 = lane & 31;
  const int fb = f * 256;
  const int hh = l5 >> 2, bb = l5 & 3;  // stage-B/C lane coords
  // stage twiddle powers (exact, no chains): pw1[j-1]=W256^{l5*j}, pw2[j-1]=W256^{8bb*j}
  cpx pw1[7], pw2[7];
#pragma unroll
  for (int j = 1; j <= 7; ++j) pw1[j - 1] = tw[512 * l5 * j];
#pragma unroll
  for (int j = 1; j <= 7; ++j) pw2[j - 1] = tw[4096 * bb * j];
  __syncthreads();
#pragma unroll
  for (int p2 = 0; p2 < 2; ++p2) {
    const int n1l = 8 * p2 + 2 * wid + f;
    const int n1 = n1b + n1l;
    cpx v[8];
#pragma unroll
    for (int j = 0; j < 4; ++j) v[j] = h2c(tz[18 * (32 * j + l5) + n1l]);
    fft8h<-1>(v);  // over j -> k0 (upper half zero)
#pragma unroll
    for (int k0 = 1; k0 < 8; ++k0) v[k0] = cmul(v[k0], pw1[k0 - 1]);
#pragma unroll
    for (int k0 = 0; k0 < 8; ++k0) X[fb + 32 * k0 + (l5 ^ (4 * k0))] = v[k0];
    WFENCE();
#pragma unroll
    for (int j2 = 0; j2 < 8; ++j2) v[j2] = X[fb + 32 * hh + ((4 * j2 + bb) ^ (4 * hh))];
    fft8<-1>(v);  // over j2 -> k'0   (lane: k0 = hh, t = bb)
#pragma unroll
    for (int kp = 1; kp < 8; ++kp) v[kp] = cmul(v[kp], pw2[kp - 1]);
    WFENCE();
#pragma unroll
    for (int kp = 0; kp < 8; ++kp) {
      int cc = kp & 3, gg = kp >> 2;
      X[fb + 128 * gg + 32 * cc + 8 * (bb ^ cc) + hh] = v[kp];
    }
    WFENCE();
#pragma unroll
    for (int g = 0; g < 2; ++g) {  // lane: k0 = hh, k'0 = bb + 4g
      cpx u4[4];
#pragma unroll
      for (int t = 0; t < 4; ++t) u4[t] = X[fb + 128 * g + 32 * bb + 8 * (t ^ bb) + hh];
      fft4<-1>(u4);  // over t -> k'1
#pragma unroll
      for (int k1q = 0; k1q < 4; ++k1q) {
        int k2 = hh + 8 * bb + 32 * g + 64 * k1q;
        cpx y = cmul(u4[k1q], tw[n1 * k2]);  // * W_N^{n1*k2}, direct gather
        to[17 * k2 + n1l] = c2h(y);
      }
    }
    WFENCE();
  }
  __syncthreads();
  // out: rows k2 natural, 64B granule (4 lanes x 16B)
  {
    int c = tid & 3, q = tid >> 2;
#pragma unroll
    for (int iter = 0; iter < 4; ++iter) {
      int row = q + 64 * iter;
      __half2 h0 = to[17 * row + 4 * c + 0], h1 = to[17 * row + 4 * c + 1];
      __half2 h2v = to[17 * row + 4 * c + 2], h3 = to[17 * row + 4 * c + 3];
      int4 pk;
      pk.x = *(int*)&h0; pk.y = *(int*)&h1; pk.z = *(int*)&h2v; pk.w = *(int*)&h3;
      *(int4*)(buf + ((size_t)s * NN2 + row) * NN1 + n1b + 4 * c) = pk;
    }
  }
}

// ---------------------------------------------------------------------------
// K2: one WAVE per Hermitian column pair (k2, 256-k2): both forward 512-FFTs,
// Hermitian extract + Y=X*H (both directions), both inverse 512-FFTs, conj
// big twiddle (direct gather) + 1/N, in place. No block barriers at all.
// ---------------------------------------------------------------------------
__global__ __launch_bounds__(256, 4) void k_mid(
    __half2* __restrict__ buf, const cpx* __restrict__ tw) {
  __shared__ cpx smem[4 * 1152];     // per-wave: RA[576] + RB[576]
  const int tid = threadIdx.x;
  const int lane = tid & 63;
  const int wid = tid >> 6;
  const int s = blockIdx.x >> 5;
  const int p = (blockIdx.x & 31) * 4 + wid;   // pair id in [0,128)
  const bool self = (p == 0);
  const int colA = self ? 0 : p;
  const int colB = self ? 128 : 256 - p;
  cpx* RA = smem + wid * 1152;
  cpx* RB = RA + 576;
  __half2* colpA = buf + ((size_t)s * NN2 + colA) * NN1;
  __half2* colpB = buf + ((size_t)s * NN2 + colB) * NN1;

  const int jm = lane >> 3, mo = lane & 7;
  const int kbase = jm + 8 * mo;

  // stage twiddle powers (exact gathers): pA[j-1]=W512^{lane*j}, pB[j-1]=W512^{8mo*j}
  cpx pA[7], pB[7];
#pragma unroll
  for (int j = 1; j <= 7; ++j) pA[j - 1] = tw[256 * lane * j];
#pragma unroll
  for (int j = 1; j <= 7; ++j) pB[j - 1] = tw[2048 * mo * j];

  cpx va[8], vb[8];
#pragma unroll
  for (int k = 0; k < 8; ++k) va[k] = h2c(colpA[lane + 64 * k]);
#pragma unroll
  for (int k = 0; k < 8; ++k) vb[k] = h2c(colpB[lane + 64 * k]);

  // ---- forward 512 = 8x8x8, both columns interleaved ----
  fft8<-1>(va); fft8<-1>(vb);
#pragma unroll
  for (int j = 1; j < 8; ++j) { va[j] = cmul(va[j], pA[j - 1]); vb[j] = cmul(vb[j], pA[j - 1]); }
#pragma unroll
  for (int j = 0; j < 8; ++j) { int a = 64 * j + (lane ^ (8 * j)); RA[a] = va[j]; RB[a] = vb[j]; }
  WFENCE();
#pragma unroll
  for (int m1 = 0; m1 < 8; ++m1) { int a = 64 * jm + ((mo + 8 * m1) ^ (8 * jm)); va[m1] = RA[a]; vb[m1] = RB[a]; }
  fft8<-1>(va); fft8<-1>(vb);
#pragma unroll
  for (int r0 = 1; r0 < 8; ++r0) { va[r0] = cmul(va[r0], pB[r0 - 1]); vb[r0] = cmul(vb[r0], pB[r0 - 1]); }
  WFENCE();
#pragma unroll
  for (int r0 = 0; r0 < 8; ++r0) { int a = 9 * (8 * jm + r0) + mo; RA[a] = va[r0]; RB[a] = vb[r0]; }
  WFENCE();
#pragma unroll
  for (int m0 = 0; m0 < 8; ++m0) { va[m0] = RA[9 * lane + m0]; vb[m0] = RB[9 * lane + m0]; }
  fft8<-1>(va); fft8<-1>(vb);  // F at k = kbase + 64*r1
  WFENCE();
#pragma unroll
  for (int r1 = 0; r1 < 8; ++r1) { int k = kbase + 64 * r1; int a = k + (k >> 3); RA[a] = va[r1]; RB[a] = vb[r1]; }
  WFENCE();
  // Hermitian extract + product, column A (partner = B unless self)
  {
    cpx q[8];
#pragma unroll
    for (int r1 = 0; r1 < 8; ++r1) {
      int k = kbase + 64 * r1;
      int pk = self ? ((512 - k) & 511) : (511 - k);
      q[r1] = (self ? RA : RB)[pk + (pk >> 3)];
    }
#pragma unroll
    for (int r1 = 0; r1 < 8; ++r1) {
      cpx z1 = va[r1], qq = q[r1], Xf2, Hf2;
      // Xf2 = (z1.x + q.x, z1.y - q.y) = 2*Xf ; Hf2 = (z1.y + q.y, q.x - z1.x) = 2*Hf
      asm("v_pk_add_f32 %0, %1, %2 neg_hi:[0,1]" : "=v"(Xf2) : "v"(z1), "v"(qq));
      asm("v_pk_add_f32 %0, %1, %2 op_sel:[1,1] op_sel_hi:[0,0] neg_hi:[1,0]" : "=v"(Hf2) : "v"(z1), "v"(qq));
      va[r1] = cmul(Xf2, Hf2);  // 4*X*H ; 0.25 folded into final twiddle
    }
  }
  // column B (partner = A unless self; reversal is 511-k in both cases)
  {
    cpx q[8];
#pragma unroll
    for (int r1 = 0; r1 < 8; ++r1) {
      int k = kbase + 64 * r1;
      int pk = 511 - k;
      q[r1] = (self ? RB : RA)[pk + (pk >> 3)];
    }
#pragma unroll
    for (int r1 = 0; r1 < 8; ++r1) {
      cpx z1 = vb[r1], qq = q[r1], Xf2, Hf2;
      asm("v_pk_add_f32 %0, %1, %2 neg_hi:[0,1]" : "=v"(Xf2) : "v"(z1), "v"(qq));
      asm("v_pk_add_f32 %0, %1, %2 op_sel:[1,1] op_sel_hi:[0,0] neg_hi:[1,0]" : "=v"(Hf2) : "v"(z1), "v"(qq));
      vb[r1] = cmul(Xf2, Hf2);
    }
  }
  WFENCE();
#pragma unroll
  for (int r1 = 0; r1 < 8; ++r1) { int k = kbase + 64 * r1; int a = k + (k >> 3); RA[a] = va[r1]; RB[a] = vb[r1]; }
  WFENCE();
#pragma unroll
  for (int kk = 0; kk < 8; ++kk) { int ci = lane + 64 * kk; int a = ci + (ci >> 3); va[kk] = RA[a]; vb[kk] = RB[a]; }

  // ---- inverse 512, both columns interleaved ----
  fft8<1>(va); fft8<1>(vb);
#pragma unroll
  for (int j = 1; j < 8; ++j) { va[j] = cmulc(va[j], pA[j - 1]); vb[j] = cmulc(vb[j], pA[j - 1]); }
  WFENCE();
#pragma unroll
  for (int j = 0; j < 8; ++j) { int a = 64 * j + (lane ^ (8 * j)); RA[a] = va[j]; RB[a] = vb[j]; }
  WFENCE();
#pragma unroll
  for (int m1 = 0; m1 < 8; ++m1) { int a = 64 * jm + ((mo + 8 * m1) ^ (8 * jm)); va[m1] = RA[a]; vb[m1] = RB[a]; }
  fft8<1>(va); fft8<1>(vb);
#pragma unroll
  for (int r0 = 1; r0 < 8; ++r0) { va[r0] = cmulc(va[r0], pB[r0 - 1]); vb[r0] = cmulc(vb[r0], pB[r0 - 1]); }
  WFENCE();
#pragma unroll
  for (int r0 = 0; r0 < 8; ++r0) { int a = 9 * (8 * jm + r0) + mo; RA[a] = va[r0]; RB[a] = vb[r0]; }
  WFENCE();
#pragma unroll
  for (int m0 = 0; m0 < 8; ++m0) { va[m0] = RA[9 * lane + m0]; vb[m0] = RB[9 * lane + m0]; }
  fft8<1>(va); fft8<1>(vb);  // y512 at n1 = kbase + 64*r1, unnormalized

  // final: * conj(W_N^{n1*k2}) * (0.25/N), direct gathers, per column
  const float invN4 = 0.25f / (float)NFFT;
  const cpx invc = mkc(invN4, invN4);
  WFENCE();
#pragma unroll
  for (int r1 = 0; r1 < 8; ++r1) {
    int n1 = kbase + 64 * r1;
    cpx tA = cscale(tw[n1 * colA], invc);
    cpx tB = cscale(tw[n1 * colB], invc);
    cpx yA = cmulc(va[r1], tA);
    cpx yB = cmulc(vb[r1], tB);
    int a = n1 + (n1 >> 3);
    RA[a] = yA; RB[a] = yB;
  }
  WFENCE();
#pragma unroll
  for (int u = 0; u < 8; ++u) {
    int ci = lane + 64 * u; int a = ci + (ci >> 3);
    colpA[ci] = c2h(RA[a]);
    colpB[ci] = c2h(RB[a]);
  }
}

// ---------------------------------------------------------------------------
// K3: inverse FFT-256 over k2 for 16 n1 per block; write Re(y), n2 < 128.
// Exact adjoint-with-conjugate of K1 (conj twiddles via cmulc + gathers).
// ---------------------------------------------------------------------------
__global__ __launch_bounds__(256, 3) void k_inv_outer(
    const __half2* __restrict__ buf, float* __restrict__ out,
    const cpx* __restrict__ tw) {
  __shared__ __half2 ti[16 * 257];   // in tile [n1l][k2], stride 257
  __shared__ cpx xch[4 * 512];
  __shared__ float ty[128 * 17];     // y tile [n2][n1l], stride 17
  const int tid = threadIdx.x;
  const int lane = tid & 63;
  const int wid = tid >> 6;
  const int s = blockIdx.x >> 5;
  const int n1b = (blockIdx.x & 31) * 16;
  // stage-in: rows k2, 64B granule
  {
    int c = tid & 3, q = tid >> 2;
#pragma unroll
    for (int iter = 0; iter < 4; ++iter) {
      int row = q + 64 * iter;
      int4 pk = *(const int4*)(buf + ((size_t)s * NN2 + row) * NN1 + n1b + 4 * c);
      __half2 hv[4];
      *(int*)&hv[0] = pk.x; *(int*)&hv[1] = pk.y; *(int*)&hv[2] = pk.z; *(int*)&hv[3] = pk.w;
#pragma unroll
      for (int j = 0; j < 4; ++j) ti[(4 * c + j) * 257 + row] = hv[j];
    }
  }
  cpx* X = xch + wid * 512;
  const int f = lane >> 5;
  const int l5 = lane & 31;
  const int fb = f * 256;
  const int hh = l5 >> 2, bb = l5 & 3;
  cpx pw1[7], pw2[7];
#pragma unroll
  for (int j = 1; j <= 7; ++j) pw1[j - 1] = tw[512 * l5 * j];
#pragma unroll
  for (int j = 1; j <= 7; ++j) pw2[j - 1] = tw[4096 * bb * j];
  __syncthreads();
#pragma unroll
  for (int p2 = 0; p2 < 2; ++p2) {
    const int n1l = 8 * p2 + 2 * wid + f;
    // load k-layout: k = hh + 8bb + 32g + 64k'1
    cpx v2[2][4];
#pragma unroll
    for (int g = 0; g < 2; ++g)
#pragma unroll
      for (int k1q = 0; k1q < 4; ++k1q)
        v2[g][k1q] = h2c(ti[n1l * 257 + hh + 8 * bb + 32 * g + 64 * k1q]);
    // ifft4 over k'1 -> t
#pragma unroll
    for (int g = 0; g < 2; ++g) fft4<1>(v2[g]);
    // E2^T: write stage-C layout -> scratch
#pragma unroll
    for (int g = 0; g < 2; ++g)
#pragma unroll
      for (int t = 0; t < 4; ++t)
        X[fb + 128 * g + 32 * bb + 8 * (t ^ bb) + hh] = v2[g][t];
    WFENCE();
    cpx v[8];
#pragma unroll
    for (int kp = 0; kp < 8; ++kp) {
      int cc = kp & 3, gg = kp >> 2;
      v[kp] = X[fb + 128 * gg + 32 * cc + 8 * (bb ^ cc) + hh];  // lane: k0=hh, t=bb
    }
#pragma unroll
    for (int kp = 1; kp < 8; ++kp) v[kp] = cmulc(v[kp], pw2[kp - 1]);  // conj W32^{t*k'0}
    fft8<1>(v);  // over k'0 -> j2
    WFENCE();
#pragma unroll
    for (int j2 = 0; j2 < 8; ++j2) X[fb + 32 * hh + ((4 * j2 + bb) ^ (4 * hh))] = v[j2];
    WFENCE();
#pragma unroll
    for (int k0 = 0; k0 < 8; ++k0) v[k0] = X[fb + 32 * k0 + (l5 ^ (4 * k0))];
#pragma unroll
    for (int k0 = 1; k0 < 8; ++k0) v[k0] = cmulc(v[k0], pw1[k0 - 1]);  // conj W256^{l5*k0}
    fft8<1>(v);  // over k0 -> j : v[j] = y[32j + l5]
#pragma unroll
    for (int j = 0; j < 4; ++j) ty[17 * (32 * j + l5) + n1l] = v[j].x;
    WFENCE();
  }
  __syncthreads();
  // out: y[n1 + 512*n2], n2 < 128; 2 lanes x 32B = 64B rows
  {
    int e = tid & 1, n2 = tid >> 1;
    float* op = out + (size_t)s * TLEN + (size_t)512 * n2 + n1b + 8 * e;
    float4 o0, o1;
    o0.x = ty[17 * n2 + 8 * e + 0]; o0.y = ty[17 * n2 + 8 * e + 1];
    o0.z = ty[17 * n2 + 8 * e + 2]; o0.w = ty[17 * n2 + 8 * e + 3];
    o1.x = ty[17 * n2 + 8 * e + 4]; o1.y = ty[17 * n2 + 8 * e + 5];
    o1.z = ty[17 * n2 + 8 * e + 6]; o1.w = ty[17 * n2 + 8 * e + 7];
    *(float4*)op = o0;
    *(float4*)(op + 4) = o1;
  }
}

extern "C" void kernel_launch(void* const* d_in, const int* in_sizes, int n_in,
                              void* d_out, int out_size, void* d_ws, size_t ws_size,
                              hipStream_t stream) {
  (void)n_in; (void)out_size; (void)ws_size;
  const float* x = (const float*)d_in[0];
  const float* h = (const float*)d_in[1];
  float* out = (float*)d_out;
  cpx* tw = (cpx*)d_ws;
  __half2* buf = (__half2*)((char*)d_ws + (size_t)(2 * 1024 * 1024));
  int seqs = in_sizes[0] / TLEN;  // 8*64 = 512
  k_init_tw<<<NFFT / 256, 256, 0, stream>>>(tw);
  k_fwd_inner<<<seqs * 32, 256, 0, stream>>>(x, h, buf, tw);
  k_mid<<<seqs * 32, 256, 0, stream>>>(buf, tw);
  k_inv_outer<<<seqs * 32, 256, 0, stream>>>(buf, out, tw);
}

// Round 3
// 758.327 us; speedup vs baseline: 1.5242x; 1.5242x over previous
//
#include <hip/hip_runtime.h>
#include <hip/hip_bf16.h>
#include <hip/hip_fp16.h>
#include <math.h>

// Causal conv via four-step FFT, N = 2T = 131072 = N1(512) x N2(256).
// z = bf16(x) + i*h ; one complex FFT serves both real signals.
// n = n1 + 512*n2 (n1 in [0,512), n2 in [0,256), nonzero n2 < 128).
// buf[seq][k2][n1] half2, k2 NATURAL order (256 rows x 512).
// ws: [0,1MiB) cpx tw[m] = exp(-2pi i m/N); [2MiB,+256MiB) buf.
//
// R1: packed-FP32 complex arithmetic (VOP3P v_pk_*_f32).
// R2: k_mid = one wave per Hermitian column pair (2x ILP, no barriers).
// R3: NO divergent twiddle gathers — every twiddle set = 1 seed load +
//     short register chain (R2's 46 gathers/wave serialized the TA pipe).

#define TLEN 65536
#define NFFT 131072
#define NN1 512
#define NN2 256

#define WFENCE() asm volatile("s_waitcnt lgkmcnt(0)" ::: "memory")

typedef float cpx __attribute__((ext_vector_type(2)));

static __device__ __forceinline__ cpx mkc(float a, float b) { cpx r; r.x = a; r.y = b; return r; }
static __device__ __forceinline__ cpx h2c(__half2 h) { float2 f = __half22float2(h); return mkc(f.x, f.y); }
static __device__ __forceinline__ __half2 c2h(cpx c) { return __float22half2_rn(make_float2(c.x, c.y)); }

// ---- packed complex primitives (one VOP3P inst per complex add/sub) ----
static __device__ __forceinline__ cpx cadd(cpx a, cpx b) {
  cpx d; asm("v_pk_add_f32 %0, %1, %2" : "=v"(d) : "v"(a), "v"(b)); return d;
}
static __device__ __forceinline__ cpx csub(cpx a, cpx b) {
  cpx d; asm("v_pk_add_f32 %0, %1, %2 neg_lo:[0,1] neg_hi:[0,1]" : "=v"(d) : "v"(a), "v"(b)); return d;
}
static __device__ __forceinline__ cpx cscale(cpx a, cpx c) {
  cpx d; asm("v_pk_mul_f32 %0, %1, %2" : "=v"(d) : "v"(a), "v"(c)); return d;
}
// d = a*b : t = (a.x*b.x, a.x*b.y); d = (-a.y*b.y + t.lo, a.y*b.x + t.hi)
static __device__ __forceinline__ cpx cmul(cpx a, cpx b) {
  cpx t, d;
  asm("v_pk_mul_f32 %0, %1, %2 op_sel:[0,0] op_sel_hi:[0,1]" : "=v"(t) : "v"(a), "v"(b));
  asm("v_pk_fma_f32 %0, %1, %2, %3 op_sel:[1,1,0] op_sel_hi:[1,0,1] neg_lo:[1,0,0]"
      : "=v"(d) : "v"(a), "v"(b), "v"(t));
  return d;
}
// d = a*conj(b) : (a.x b.x + a.y b.y, a.y b.x - a.x b.y)
static __device__ __forceinline__ cpx cmulc(cpx a, cpx b) {
  cpx t, d;
  asm("v_pk_mul_f32 %0, %1, %2 op_sel:[0,0] op_sel_hi:[0,1]" : "=v"(t) : "v"(a), "v"(b));
  asm("v_pk_fma_f32 %0, %1, %2, %3 op_sel:[1,1,0] op_sel_hi:[1,0,1] neg_hi:[0,0,1]"
      : "=v"(d) : "v"(a), "v"(b), "v"(t));
  return d;
}
// d = s*i*a : S=+1 -> (-a.y, a.x) ; S=-1 -> (a.y, -a.x)
template <int S> static __device__ __forceinline__ cpx cmuli(cpx a) {
  cpx z = mkc(0.f, 0.f); cpx d;
  if constexpr (S == 1)
    asm("v_pk_add_f32 %0, %1, %2 op_sel:[1,0] op_sel_hi:[0,0] neg_lo:[1,0]" : "=v"(d) : "v"(a), "v"(z));
  else
    asm("v_pk_add_f32 %0, %1, %2 op_sel:[1,0] op_sel_hi:[0,0] neg_hi:[1,0]" : "=v"(d) : "v"(a), "v"(z));
  return d;
}
// C * (d.x - s d.y, s d.x + d.y)
template <int S> static __device__ __forceinline__ cpx cw1(cpx d, cpx Cc) {
  cpx u;
  if constexpr (S == -1)
    asm("v_pk_add_f32 %0, %1, %1 op_sel:[0,1] op_sel_hi:[1,0] neg_hi:[0,1]" : "=v"(u) : "v"(d));
  else
    asm("v_pk_add_f32 %0, %1, %1 op_sel:[0,1] op_sel_hi:[0,1] neg_lo:[0,1]" : "=v"(u) : "v"(d));
  return cscale(u, Cc);
}
// C * (-d.x - s d.y, s d.x - d.y)
template <int S> static __device__ __forceinline__ cpx cw3(cpx d, cpx Cc) {
  cpx u;
  if constexpr (S == -1)
    asm("v_pk_add_f32 %0, %1, %1 op_sel:[1,0] op_sel_hi:[0,1] neg_lo:[0,1] neg_hi:[1,1]" : "=v"(u) : "v"(d));
  else
    asm("v_pk_add_f32 %0, %1, %1 op_sel:[0,1] op_sel_hi:[0,1] neg_lo:[1,1] neg_hi:[0,1]" : "=v"(u) : "v"(d));
  return cscale(u, Cc);
}

// out[k] = sum_j in[j] * W8^{S*jk}, W8 = e^{-2pi i/8}. Natural order.
template <int S>
__device__ __forceinline__ void fft8(cpx v[8]) {
  cpx Cc; Cc.x = 0.70710678118654752f; Cc.y = 0.70710678118654752f;
  cpx b0 = cadd(v[0], v[4]), b4 = csub(v[0], v[4]);
  cpx b1 = cadd(v[1], v[5]), d1 = csub(v[1], v[5]);
  cpx b2 = cadd(v[2], v[6]), d2 = csub(v[2], v[6]);
  cpx b3 = cadd(v[3], v[7]), d3 = csub(v[3], v[7]);
  cpx b5 = cw1<S>(d1, Cc);
  cpx b6 = cmuli<S>(d2);
  cpx b7 = cw3<S>(d3, Cc);
  cpx c0 = cadd(b0, b2), c2 = csub(b0, b2);
  cpx c1 = cadd(b1, b3), e3 = csub(b1, b3);
  cpx c3 = cmuli<S>(e3);
  cpx c4 = cadd(b4, b6), c6 = csub(b4, b6);
  cpx c5 = cadd(b5, b7), e7 = csub(b5, b7);
  cpx c7 = cmuli<S>(e7);
  v[0] = cadd(c0, c1); v[4] = csub(c0, c1);
  v[2] = cadd(c2, c3); v[6] = csub(c2, c3);
  v[1] = cadd(c4, c5); v[5] = csub(c4, c5);
  v[3] = cadd(c6, c7); v[7] = csub(c6, c7);
}

// fft8 with v[4..7] == 0 implied (zero-padded upper half): first level free.
template <int S>
__device__ __forceinline__ void fft8h(cpx v[8]) {
  cpx Cc; Cc.x = 0.70710678118654752f; Cc.y = 0.70710678118654752f;
  cpx b5 = cw1<S>(v[1], Cc);
  cpx b6 = cmuli<S>(v[2]);
  cpx b7 = cw3<S>(v[3], Cc);
  cpx c0 = cadd(v[0], v[2]), c2 = csub(v[0], v[2]);
  cpx c1 = cadd(v[1], v[3]), e3 = csub(v[1], v[3]);
  cpx c3 = cmuli<S>(e3);
  cpx c4 = cadd(v[0], b6), c6 = csub(v[0], b6);
  cpx c5 = cadd(b5, b7), e7 = csub(b5, b7);
  cpx c7 = cmuli<S>(e7);
  v[0] = cadd(c0, c1); v[4] = csub(c0, c1);
  v[2] = cadd(c2, c3); v[6] = csub(c2, c3);
  v[1] = cadd(c4, c5); v[5] = csub(c4, c5);
  v[3] = cadd(c6, c7); v[7] = csub(c6, c7);
}

template <int S>
__device__ __forceinline__ void fft4(cpx v[4]) {
  cpx t0 = cadd(v[0], v[2]), t1 = csub(v[0], v[2]);
  cpx t2 = cadd(v[1], v[3]), t3 = csub(v[1], v[3]);
  cpx it3 = cmuli<S>(t3);
  v[0] = cadd(t0, t2); v[2] = csub(t0, t2);
  v[1] = cadd(t1, it3); v[3] = csub(t1, it3);
}

__global__ void k_init_tw(cpx* __restrict__ tw) {
  int m = blockIdx.x * 256 + threadIdx.x;
  double ang = (double)m * (-2.0 * 3.14159265358979323846 / (double)NFFT);
  tw[m] = mkc((float)cos(ang), (float)sin(ang));
}

// ---------------------------------------------------------------------------
// K1: forward FFT-256 over n2 for 16 n1 per block + twiddle W_N^{n1 k2}.
// Register FFT 256 = 8x8x4. Stage twiddles: 1 seed load + register chain.
// Big twiddle: wb=tw[n1*c0] (1 gather) + wst=tw[32*n1] (2-line) -> wg[8] chain.
// ---------------------------------------------------------------------------
__global__ __launch_bounds__(256, 3) void k_fwd_inner(
    const float* __restrict__ x, const float* __restrict__ h,
    __half2* __restrict__ buf, const cpx* __restrict__ tw) {
  __shared__ __half2 tz[128 * 18];   // z tile [n2][n1], stride 18
  __shared__ cpx xch[4 * 512];       // per-wave exchange scratch
  __shared__ __half2 to[256 * 17];   // out tile [k2][n1l], stride 17
  const int tid = threadIdx.x;
  const int lane = tid & 63;
  const int wid = tid >> 6;
  const int s = blockIdx.x >> 5;
  const int n1b = (blockIdx.x & 31) * 16;
  // stage-in: 64B-granule rows (4 lanes x float4)
  const float* xp = x + (size_t)s * TLEN;
  const float* hp = h + (size_t)s * TLEN;
  {
    int a = tid & 3, q = tid >> 2;
#pragma unroll
    for (int iter = 0; iter < 2; ++iter) {
      int n2 = q + 64 * iter;
      size_t gi = (size_t)(n1b + 4 * a) + (size_t)512 * n2;
      float4 xv = *(const float4*)(xp + gi);
      float4 hv = *(const float4*)(hp + gi);
      float xs[4] = {xv.x, xv.y, xv.z, xv.w};
      float hs[4] = {hv.x, hv.y, hv.z, hv.w};
#pragma unroll
      for (int c = 0; c < 4; ++c) {
        float xb = __bfloat162float(__float2bfloat16(xs[c]));
        tz[18 * n2 + 4 * a + c] = __float22half2_rn(make_float2(xb, hs[c]));
      }
    }
  }
  cpx* X = xch + wid * 512;
  const int f = lane >> 5;
  const int l5 = lane & 31;
  const int fb = f * 256;
  const int hh = l5 >> 2, bb = l5 & 3;  // stage-B/C lane coords
  // stage twiddles: seed + chain (pw1[j-1]=W256^{l5*j}, pw2[j-1]=W256^{8bb*j})
  cpx pw1[7], pw2[7];
  pw1[0] = tw[512 * l5];
  pw2[0] = tw[4096 * bb];
#pragma unroll
  for (int j = 1; j < 7; ++j) pw1[j] = cmul(pw1[j - 1], pw1[0]);
#pragma unroll
  for (int j = 1; j < 7; ++j) pw2[j] = cmul(pw2[j - 1], pw2[0]);
  __syncthreads();
#pragma unroll
  for (int p2 = 0; p2 < 2; ++p2) {
    const int n1l = 8 * p2 + 2 * wid + f;
    const int n1 = n1b + n1l;
    // big-twiddle seeds issued early; chain built at use site
    const cpx wb = tw[n1 * (hh + 8 * bb)];   // W_N^{n1*c0}, one gather
    const cpx wst = tw[32 * n1];             // W_N^{32*n1}, 2 lines per wave
    cpx v[8];
#pragma unroll
    for (int j = 0; j < 4; ++j) v[j] = h2c(tz[18 * (32 * j + l5) + n1l]);
    fft8h<-1>(v);  // over j -> k0 (upper half zero)
#pragma unroll
    for (int k0 = 1; k0 < 8; ++k0) v[k0] = cmul(v[k0], pw1[k0 - 1]);
#pragma unroll
    for (int k0 = 0; k0 < 8; ++k0) X[fb + 32 * k0 + (l5 ^ (4 * k0))] = v[k0];
    WFENCE();
#pragma unroll
    for (int j2 = 0; j2 < 8; ++j2) v[j2] = X[fb + 32 * hh + ((4 * j2 + bb) ^ (4 * hh))];
    fft8<-1>(v);  // over j2 -> k'0   (lane: k0 = hh, t = bb)
#pragma unroll
    for (int kp = 1; kp < 8; ++kp) v[kp] = cmul(v[kp], pw2[kp - 1]);
    WFENCE();
#pragma unroll
    for (int kp = 0; kp < 8; ++kp) {
      int cc = kp & 3, gg = kp >> 2;
      X[fb + 128 * gg + 32 * cc + 8 * (bb ^ cc) + hh] = v[kp];
    }
    // wg[m] = W_N^{n1*(c0+32m)} built while LDS drains
    cpx wg[8];
    wg[0] = wb;
#pragma unroll
    for (int m = 1; m < 8; ++m) wg[m] = cmul(wg[m - 1], wst);
    WFENCE();
#pragma unroll
    for (int g = 0; g < 2; ++g) {  // lane: k0 = hh, k'0 = bb + 4g
      cpx u4[4];
#pragma unroll
      for (int t = 0; t < 4; ++t) u4[t] = X[fb + 128 * g + 32 * bb + 8 * (t ^ bb) + hh];
      fft4<-1>(u4);  // over t -> k'1
#pragma unroll
      for (int k1q = 0; k1q < 4; ++k1q) {
        int k2 = hh + 8 * bb + 32 * g + 64 * k1q;
        cpx y = cmul(u4[k1q], wg[g + 2 * k1q]);  // * W_N^{n1*k2}
        to[17 * k2 + n1l] = c2h(y);
      }
    }
    WFENCE();
  }
  __syncthreads();
  // out: rows k2 natural, 64B granule (4 lanes x 16B)
  {
    int c = tid & 3, q = tid >> 2;
#pragma unroll
    for (int iter = 0; iter < 4; ++iter) {
      int row = q + 64 * iter;
      __half2 h0 = to[17 * row + 4 * c + 0], h1 = to[17 * row + 4 * c + 1];
      __half2 h2v = to[17 * row + 4 * c + 2], h3 = to[17 * row + 4 * c + 3];
      int4 pk;
      pk.x = *(int*)&h0; pk.y = *(int*)&h1; pk.z = *(int*)&h2v; pk.w = *(int*)&h3;
      *(int4*)(buf + ((size_t)s * NN2 + row) * NN1 + n1b + 4 * c) = pk;
    }
  }
}

// ---------------------------------------------------------------------------
// K2: one WAVE per Hermitian column pair (k2, 256-k2): both forward 512-FFTs,
// Hermitian extract + Y=X*H (both directions), both inverse 512-FFTs, conj
// big twiddle (seed+chain) + 1/N, in place. No block barriers at all.
// ---------------------------------------------------------------------------
__global__ __launch_bounds__(256, 4) void k_mid(
    __half2* __restrict__ buf, const cpx* __restrict__ tw) {
  __shared__ cpx smem[4 * 1152];     // per-wave: RA[576] + RB[576]
  const int tid = threadIdx.x;
  const int lane = tid & 63;
  const int wid = tid >> 6;
  const int s = blockIdx.x >> 5;
  const int p = (blockIdx.x & 31) * 4 + wid;   // pair id in [0,128)
  const bool self = (p == 0);
  const int colA = self ? 0 : p;
  const int colB = self ? 128 : 256 - p;
  cpx* RA = smem + wid * 1152;
  cpx* RB = RA + 576;
  __half2* colpA = buf + ((size_t)s * NN2 + colA) * NN1;
  __half2* colpB = buf + ((size_t)s * NN2 + colB) * NN1;

  const int jm = lane >> 3, mo = lane & 7;
  const int kbase = jm + 8 * mo;

  cpx va[8], vb[8];
#pragma unroll
  for (int k = 0; k < 8; ++k) va[k] = h2c(colpA[lane + 64 * k]);
#pragma unroll
  for (int k = 0; k < 8; ++k) vb[k] = h2c(colpB[lane + 64 * k]);

  // stage twiddles: seed + chain (pA[j-1]=W512^{lane*j}, pB[j-1]=W512^{8mo*j})
  cpx pA[7], pB[7];
  pA[0] = tw[256 * lane];
  pB[0] = tw[2048 * mo];
#pragma unroll
  for (int j = 1; j < 7; ++j) pA[j] = cmul(pA[j - 1], pA[0]);
#pragma unroll
  for (int j = 1; j < 7; ++j) pB[j] = cmul(pB[j - 1], pB[0]);
  // final-twiddle seeds (used at the very end; issued early to hide latency)
  const cpx twA0 = tw[kbase * colA];   // one gather
  const cpx twB0 = tw[kbase * colB];   // one gather
  const cpx tsA = tw[64 * colA];       // wave-uniform
  const cpx tsB = tw[64 * colB];       // wave-uniform

  // ---- forward 512 = 8x8x8, both columns interleaved ----
  fft8<-1>(va); fft8<-1>(vb);
#pragma unroll
  for (int j = 1; j < 8; ++j) { va[j] = cmul(va[j], pA[j - 1]); vb[j] = cmul(vb[j], pA[j - 1]); }
#pragma unroll
  for (int j = 0; j < 8; ++j) { int a = 64 * j + (lane ^ (8 * j)); RA[a] = va[j]; RB[a] = vb[j]; }
  WFENCE();
#pragma unroll
  for (int m1 = 0; m1 < 8; ++m1) { int a = 64 * jm + ((mo + 8 * m1) ^ (8 * jm)); va[m1] = RA[a]; vb[m1] = RB[a]; }
  fft8<-1>(va); fft8<-1>(vb);
#pragma unroll
  for (int r0 = 1; r0 < 8; ++r0) { va[r0] = cmul(va[r0], pB[r0 - 1]); vb[r0] = cmul(vb[r0], pB[r0 - 1]); }
  WFENCE();
#pragma unroll
  for (int r0 = 0; r0 < 8; ++r0) { int a = 9 * (8 * jm + r0) + mo; RA[a] = va[r0]; RB[a] = vb[r0]; }
  WFENCE();
#pragma unroll
  for (int m0 = 0; m0 < 8; ++m0) { va[m0] = RA[9 * lane + m0]; vb[m0] = RB[9 * lane + m0]; }
  fft8<-1>(va); fft8<-1>(vb);  // F at k = kbase + 64*r1
  WFENCE();
#pragma unroll
  for (int r1 = 0; r1 < 8; ++r1) { int k = kbase + 64 * r1; int a = k + (k >> 3); RA[a] = va[r1]; RB[a] = vb[r1]; }
  WFENCE();
  // Hermitian extract + product, column A (partner = B unless self)
  {
    cpx q[8];
#pragma unroll
    for (int r1 = 0; r1 < 8; ++r1) {
      int k = kbase + 64 * r1;
      int pk = self ? ((512 - k) & 511) : (511 - k);
      q[r1] = (self ? RA : RB)[pk + (pk >> 3)];
    }
#pragma unroll
    for (int r1 = 0; r1 < 8; ++r1) {
      cpx z1 = va[r1], qq = q[r1], Xf2, Hf2;
      // Xf2 = (z1.x + q.x, z1.y - q.y) = 2*Xf ; Hf2 = (z1.y + q.y, q.x - z1.x) = 2*Hf
      asm("v_pk_add_f32 %0, %1, %2 neg_hi:[0,1]" : "=v"(Xf2) : "v"(z1), "v"(qq));
      asm("v_pk_add_f32 %0, %1, %2 op_sel:[1,1] op_sel_hi:[0,0] neg_hi:[1,0]" : "=v"(Hf2) : "v"(z1), "v"(qq));
      va[r1] = cmul(Xf2, Hf2);  // 4*X*H ; 0.25 folded into final twiddle
    }
  }
  // column B (partner = A unless self; reversal is 511-k in both cases)
  {
    cpx q[8];
#pragma unroll
    for (int r1 = 0; r1 < 8; ++r1) {
      int k = kbase + 64 * r1;
      int pk = 511 - k;
      q[r1] = (self ? RB : RA)[pk + (pk >> 3)];
    }
#pragma unroll
    for (int r1 = 0; r1 < 8; ++r1) {
      cpx z1 = vb[r1], qq = q[r1], Xf2, Hf2;
      asm("v_pk_add_f32 %0, %1, %2 neg_hi:[0,1]" : "=v"(Xf2) : "v"(z1), "v"(qq));
      asm("v_pk_add_f32 %0, %1, %2 op_sel:[1,1] op_sel_hi:[0,0] neg_hi:[1,0]" : "=v"(Hf2) : "v"(z1), "v"(qq));
      vb[r1] = cmul(Xf2, Hf2);
    }
  }
  WFENCE();
#pragma unroll
  for (int r1 = 0; r1 < 8; ++r1) { int k = kbase + 64 * r1; int a = k + (k >> 3); RA[a] = va[r1]; RB[a] = vb[r1]; }
  WFENCE();
#pragma unroll
  for (int kk = 0; kk < 8; ++kk) { int ci = lane + 64 * kk; int a = ci + (ci >> 3); va[kk] = RA[a]; vb[kk] = RB[a]; }

  // ---- inverse 512, both columns interleaved ----
  fft8<1>(va); fft8<1>(vb);
#pragma unroll
  for (int j = 1; j < 8; ++j) { va[j] = cmulc(va[j], pA[j - 1]); vb[j] = cmulc(vb[j], pA[j - 1]); }
  WFENCE();
#pragma unroll
  for (int j = 0; j < 8; ++j) { int a = 64 * j + (lane ^ (8 * j)); RA[a] = va[j]; RB[a] = vb[j]; }
  WFENCE();
#pragma unroll
  for (int m1 = 0; m1 < 8; ++m1) { int a = 64 * jm + ((mo + 8 * m1) ^ (8 * jm)); va[m1] = RA[a]; vb[m1] = RB[a]; }
  fft8<1>(va); fft8<1>(vb);
#pragma unroll
  for (int r0 = 1; r0 < 8; ++r0) { va[r0] = cmulc(va[r0], pB[r0 - 1]); vb[r0] = cmulc(vb[r0], pB[r0 - 1]); }
  WFENCE();
#pragma unroll
  for (int r0 = 0; r0 < 8; ++r0) { int a = 9 * (8 * jm + r0) + mo; RA[a] = va[r0]; RB[a] = vb[r0]; }
  WFENCE();
#pragma unroll
  for (int m0 = 0; m0 < 8; ++m0) { va[m0] = RA[9 * lane + m0]; vb[m0] = RB[9 * lane + m0]; }
  fft8<1>(va); fft8<1>(vb);  // y512 at n1 = kbase + 64*r1, unnormalized

  // final: * conj(W_N^{n1*k2}) * (0.25/N); base gather + uniform-step chain
  const float invN4 = 0.25f / (float)NFFT;
  const cpx invc = mkc(invN4, invN4);
  cpx tA = cscale(twA0, invc);
  cpx tB = cscale(twB0, invc);
  WFENCE();
#pragma unroll
  for (int r1 = 0; r1 < 8; ++r1) {
    int n1 = kbase + 64 * r1;
    int a = n1 + (n1 >> 3);
    RA[a] = cmulc(va[r1], tA);
    RB[a] = cmulc(vb[r1], tB);
    if (r1 < 7) { tA = cmul(tA, tsA); tB = cmul(tB, tsB); }
  }
  WFENCE();
#pragma unroll
  for (int u = 0; u < 8; ++u) {
    int ci = lane + 64 * u; int a = ci + (ci >> 3);
    colpA[ci] = c2h(RA[a]);
    colpB[ci] = c2h(RB[a]);
  }
}

// ---------------------------------------------------------------------------
// K3: inverse FFT-256 over k2 for 16 n1 per block; write Re(y), n2 < 128.
// Exact adjoint-with-conjugate of K1 (conj twiddles via cmulc, seed+chain).
// ---------------------------------------------------------------------------
__global__ __launch_bounds__(256, 3) void k_inv_outer(
    const __half2* __restrict__ buf, float* __restrict__ out,
    const cpx* __restrict__ tw) {
  __shared__ __half2 ti[16 * 257];   // in tile [n1l][k2], stride 257
  __shared__ cpx xch[4 * 512];
  __shared__ float ty[128 * 17];     // y tile [n2][n1l], stride 17
  const int tid = threadIdx.x;
  const int lane = tid & 63;
  const int wid = tid >> 6;
  const int s = blockIdx.x >> 5;
  const int n1b = (blockIdx.x & 31) * 16;
  // stage-in: rows k2, 64B granule
  {
    int c = tid & 3, q = tid >> 2;
#pragma unroll
    for (int iter = 0; iter < 4; ++iter) {
      int row = q + 64 * iter;
      int4 pk = *(const int4*)(buf + ((size_t)s * NN2 + row) * NN1 + n1b + 4 * c);
      __half2 hv[4];
      *(int*)&hv[0] = pk.x; *(int*)&hv[1] = pk.y; *(int*)&hv[2] = pk.z; *(int*)&hv[3] = pk.w;
#pragma unroll
      for (int j = 0; j < 4; ++j) ti[(4 * c + j) * 257 + row] = hv[j];
    }
  }
  cpx* X = xch + wid * 512;
  const int f = lane >> 5;
  const int l5 = lane & 31;
  const int fb = f * 256;
  const int hh = l5 >> 2, bb = l5 & 3;
  cpx pw1[7], pw2[7];
  pw1[0] = tw[512 * l5];
  pw2[0] = tw[4096 * bb];
#pragma unroll
  for (int j = 1; j < 7; ++j) pw1[j] = cmul(pw1[j - 1], pw1[0]);
#pragma unroll
  for (int j = 1; j < 7; ++j) pw2[j] = cmul(pw2[j - 1], pw2[0]);
  __syncthreads();
#pragma unroll
  for (int p2 = 0; p2 < 2; ++p2) {
    const int n1l = 8 * p2 + 2 * wid + f;
    // load k-layout: k = hh + 8bb + 32g + 64k'1
    cpx v2[2][4];
#pragma unroll
    for (int g = 0; g < 2; ++g)
#pragma unroll
      for (int k1q = 0; k1q < 4; ++k1q)
        v2[g][k1q] = h2c(ti[n1l * 257 + hh + 8 * bb + 32 * g + 64 * k1q]);
    // ifft4 over k'1 -> t
#pragma unroll
    for (int g = 0; g < 2; ++g) fft4<1>(v2[g]);
    // E2^T: write stage-C layout -> scratch
#pragma unroll
    for (int g = 0; g < 2; ++g)
#pragma unroll
      for (int t = 0; t < 4; ++t)
        X[fb + 128 * g + 32 * bb + 8 * (t ^ bb) + hh] = v2[g][t];
    WFENCE();
    cpx v[8];
#pragma unroll
    for (int kp = 0; kp < 8; ++kp) {
      int cc = kp & 3, gg = kp >> 2;
      v[kp] = X[fb + 128 * gg + 32 * cc + 8 * (bb ^ cc) + hh];  // lane: k0=hh, t=bb
    }
#pragma unroll
    for (int kp = 1; kp < 8; ++kp) v[kp] = cmulc(v[kp], pw2[kp - 1]);  // conj W32^{t*k'0}
    fft8<1>(v);  // over k'0 -> j2
    WFENCE();
#pragma unroll
    for (int j2 = 0; j2 < 8; ++j2) X[fb + 32 * hh + ((4 * j2 + bb) ^ (4 * hh))] = v[j2];
    WFENCE();
#pragma unroll
    for (int k0 = 0; k0 < 8; ++k0) v[k0] = X[fb + 32 * k0 + (l5 ^ (4 * k0))];
#pragma unroll
    for (int k0 = 1; k0 < 8; ++k0) v[k0] = cmulc(v[k0], pw1[k0 - 1]);  // conj W256^{l5*k0}
    fft8<1>(v);  // over k0 -> j : v[j] = y[32j + l5]
#pragma unroll
    for (int j = 0; j < 4; ++j) ty[17 * (32 * j + l5) + n1l] = v[j].x;
    WFENCE();
  }
  __syncthreads();
  // out: y[n1 + 512*n2], n2 < 128; 2 lanes x 32B = 64B rows
  {
    int e = tid & 1, n2 = tid >> 1;
    float* op = out + (size_t)s * TLEN + (size_t)512 * n2 + n1b + 8 * e;
    float4 o0, o1;
    o0.x = ty[17 * n2 + 8 * e + 0]; o0.y = ty[17 * n2 + 8 * e + 1];
    o0.z = ty[17 * n2 + 8 * e + 2]; o0.w = ty[17 * n2 + 8 * e + 3];
    o1.x = ty[17 * n2 + 8 * e + 4]; o1.y = ty[17 * n2 + 8 * e + 5];
    o1.z = ty[17 * n2 + 8 * e + 6]; o1.w = ty[17 * n2 + 8 * e + 7];
    *(float4*)op = o0;
    *(float4*)(op + 4) = o1;
  }
}

extern "C" void kernel_launch(void* const* d_in, const int* in_sizes, int n_in,
                              void* d_out, int out_size, void* d_ws, size_t ws_size,
                              hipStream_t stream) {
  (void)n_in; (void)out_size; (void)ws_size;
  const float* x = (const float*)d_in[0];
  const float* h = (const float*)d_in[1];
  float* out = (float*)d_out;
  cpx* tw = (cpx*)d_ws;
  __half2* buf = (__half2*)((char*)d_ws + (size_t)(2 * 1024 * 1024));
  int seqs = in_sizes[0] / TLEN;  // 8*64 = 512
  k_init_tw<<<NFFT / 256, 256, 0, stream>>>(tw);
  k_fwd_inner<<<seqs * 32, 256, 0, stream>>>(x, h, buf, tw);
  k_mid<<<seqs * 32, 256, 0, stream>>>(buf, tw);
  k_inv_outer<<<seqs * 32, 256, 0, stream>>>(buf, out, tw);
}